// Round 1
// baseline (3264.996 us; speedup 1.0000x reference)
//
#include <hip/hip_runtime.h>

#define T_TOTAL 512
#define CCH     128
#define HH      28
#define WWD     28
#define HW      784        // 28*28
#define NSEG    8
#define NOUT    51380224   // 512*128*784

// ---------------------------------------------------------------------------
// K0: repack w_t [o][i][tap] -> wT [tap][i][o]  (makes K2 staging coalesced)
// ---------------------------------------------------------------------------
__global__ void repack_wt(const float* __restrict__ w_t, float* __restrict__ wT) {
    int idx = blockIdx.x * 256 + threadIdx.x;
    if (idx >= CCH * CCH * 3) return;
    int o   = idx / (CCH * 3);
    int rem = idx % (CCH * 3);
    int i   = rem / 3;
    int tap = rem % 3;
    wT[((size_t)tap * CCH + i) * CCH + o] = w_t[idx];
}

// ---------------------------------------------------------------------------
// K1: spatial 3x3 conv, SAME, NCHW, fp32.  grid (4, 512), block 448.
// Each block: one frame t, 32 consecutive c_out.
// Thread: 8 c_out x 7 contiguous-w pixels; x patch in regs; w via scalar loads.
// ---------------------------------------------------------------------------
__global__ __launch_bounds__(448) void spatial_conv(
    const float* __restrict__ x, const float* __restrict__ w_sp,
    const float* __restrict__ b_sp, float* __restrict__ y)
{
    const int t       = blockIdx.y;
    const int co_base = blockIdx.x * 32;
    const int tid     = threadIdx.x;
    const int cog     = tid / 112;        // 0..3
    const int pxg     = tid % 112;        // 0..111
    const int row     = pxg / 4;          // 0..27
    const int wbase   = (pxg % 4) * 7;    // 0,7,14,21
    const int co      = co_base + cog * 8;

    float acc[8][7];
#pragma unroll
    for (int c = 0; c < 8; ++c)
#pragma unroll
        for (int j = 0; j < 7; ++j) acc[c][j] = 0.f;

    const float* xt = x + (size_t)t * CCH * HW;

    for (int ci = 0; ci < CCH; ++ci) {
        // load 3x9 patch into registers (bounds-predicated)
        float xr[3][9];
        const float* xc = xt + (size_t)ci * HW;
#pragma unroll
        for (int r = 0; r < 3; ++r) {
            int hh = row + r - 1;
            bool rok = (hh >= 0) && (hh < HH);
#pragma unroll
            for (int m = 0; m < 9; ++m) {
                int ww = wbase + m - 1;
                bool ok = rok && (ww >= 0) && (ww < WWD);
                xr[r][m] = ok ? xc[hh * WWD + ww] : 0.f;
            }
        }
        // 8 c_out * 9 taps * 7 px = 504 FMA per ci
        const float* wp = w_sp + ((size_t)co * CCH + ci) * 9;
#pragma unroll
        for (int c = 0; c < 8; ++c) {
            const float* wpc = wp + (size_t)c * CCH * 9;   // block-uniform -> s_load
#pragma unroll
            for (int kh = 0; kh < 3; ++kh) {
#pragma unroll
                for (int kw = 0; kw < 3; ++kw) {
                    float wv = wpc[kh * 3 + kw];
#pragma unroll
                    for (int j = 0; j < 7; ++j)
                        acc[c][j] = fmaf(xr[kh][j + kw], wv, acc[c][j]);
                }
            }
        }
    }

#pragma unroll
    for (int c = 0; c < 8; ++c) {
        float bv = b_sp[co + c];
        float* yp = y + ((size_t)(t * CCH + co + c)) * HW + row * WWD + wbase;
#pragma unroll
        for (int j = 0; j < 7; ++j) yp[j] = acc[c][j] + bv;
    }
}

// ---------------------------------------------------------------------------
// K2: ragged temporal conv (k=3) + bias + PReLU + residual. grid (7, 512), 448.
// K = 384 (tap-major: k = tap*128 + ci), LDS tiles: y[16][112], w[16][128].
// Thread: 8 c_out x 4 px (float4).
// ---------------------------------------------------------------------------
__global__ __launch_bounds__(448) void temporal_fuse(
    const float* __restrict__ y, const float* __restrict__ wT,
    const float* __restrict__ b_t, const float* __restrict__ alpha,
    const float* __restrict__ x, const int* __restrict__ vid_lens,
    float* __restrict__ out)
{
    __shared__ float ytile[16][112];
    __shared__ float wtile[16][128];

    const int t      = blockIdx.y;
    const int pxbase = blockIdx.x * 112;
    const int tid    = threadIdx.x;
    const int cog    = tid / 28;    // 0..15
    const int pxg    = tid % 28;    // 0..27
    const int co     = cog * 8;
    const int pxl    = pxg * 4;

    // segment boundary flags for this frame
    bool isS = false, isE = false;
    {
        int cum = 0;
        for (int s = 0; s < NSEG; ++s) {
            if (t == cum) isS = true;
            cum += vid_lens[s];
            if (t == cum - 1) isE = true;
        }
    }

    float acc[8][4];
#pragma unroll
    for (int c = 0; c < 8; ++c)
#pragma unroll
        for (int j = 0; j < 4; ++j) acc[c][j] = 0.f;

    for (int kc = 0; kc < 384; kc += 16) {
        const int tap    = kc / 128;
        const int cibase = kc % 128;
        const int ts     = t + tap - 1;
        const bool valid = (tap == 1) || (tap == 0 ? !isS : !isE);

        __syncthreads();
        // stage y tile: 16 rows x 112 px, one float4 per thread
        {
            int idx = tid * 4;
            int kk  = idx / 112;
            int col = idx % 112;
            float4 v = make_float4(0.f, 0.f, 0.f, 0.f);
            if (valid) {
                v = *(const float4*)&y[((size_t)(ts * CCH + cibase + kk)) * HW + pxbase + col];
            }
            *(float4*)&ytile[kk][col] = v;
        }
        // stage w tile: 16 x 128 = 2048 floats, coalesced
#pragma unroll
        for (int r = 0; r < 5; ++r) {
            int i = tid + r * 448;
            if (i < 2048) {
                int kk = i / 128;
                int o  = i % 128;
                wtile[kk][o] = wT[((size_t)tap * CCH + cibase + kk) * CCH + o];
            }
        }
        __syncthreads();

#pragma unroll
        for (int kk = 0; kk < 16; ++kk) {
            float4 t4 = *(const float4*)&ytile[kk][pxl];
            float yv[4] = {t4.x, t4.y, t4.z, t4.w};
#pragma unroll
            for (int c = 0; c < 8; ++c) {
                float wv = wtile[kk][co + c];
#pragma unroll
                for (int j = 0; j < 4; ++j)
                    acc[c][j] = fmaf(wv, yv[j], acc[c][j]);
            }
        }
    }

    // epilogue: + b_t, PReLU(alpha), + residual x, store
#pragma unroll
    for (int c = 0; c < 8; ++c) {
        int o = co + c;
        float bt = b_t[o];
        float al = alpha[o];
        size_t base = ((size_t)(t * CCH + o)) * HW + pxbase + pxl;
        float4 xv = *(const float4*)&x[base];
        float xr[4] = {xv.x, xv.y, xv.z, xv.w};
        float rr[4];
#pragma unroll
        for (int j = 0; j < 4; ++j) {
            float v = acc[c][j] + bt;
            v = (v >= 0.f) ? v : al * v;
            rr[j] = v + xr[j];
        }
        float4 wout = make_float4(rr[0], rr[1], rr[2], rr[3]);
        *(float4*)&out[base] = wout;
    }
}

// ---------------------------------------------------------------------------
// K3: write vid_lens (as float values) into the tail of d_out
// ---------------------------------------------------------------------------
__global__ void write_lens(const int* __restrict__ vid_lens, float* __restrict__ out) {
    int i = threadIdx.x;
    if (i < NSEG) out[NOUT + i] = (float)vid_lens[i];
}

// ---------------------------------------------------------------------------
extern "C" void kernel_launch(void* const* d_in, const int* in_sizes, int n_in,
                              void* d_out, int out_size, void* d_ws, size_t ws_size,
                              hipStream_t stream) {
    const float* x        = (const float*)d_in[0];
    const int*   vid_lens = (const int*)d_in[1];
    const float* w_sp     = (const float*)d_in[2];
    const float* b_sp     = (const float*)d_in[3];
    const float* w_t      = (const float*)d_in[4];
    const float* b_t      = (const float*)d_in[5];
    const float* alpha    = (const float*)d_in[6];
    float* out = (float*)d_out;

    float* y  = (float*)d_ws;              // 51,380,224 floats (205.5 MB)
    float* wT = y + (size_t)NOUT;          // 49,152 floats

    repack_wt<<<dim3(192), 256, 0, stream>>>(w_t, wT);
    spatial_conv<<<dim3(4, 512), 448, 0, stream>>>(x, w_sp, b_sp, y);
    temporal_fuse<<<dim3(7, 512), 448, 0, stream>>>(y, wT, b_t, alpha, x, vid_lens, out);
    write_lens<<<1, 64, 0, stream>>>(vid_lens, out);
}

// Round 2
// 782.532 us; speedup vs baseline: 4.1723x; 4.1723x over previous
//
#include <hip/hip_runtime.h>

#define TT   512
#define CH   128
#define HWP  784        // 28*28
#define NSEG 8
#define NOUT 51380224   // 512*128*784

typedef short bf16x8  __attribute__((ext_vector_type(8)));
typedef float f32x4   __attribute__((ext_vector_type(4)));
typedef int   i32x4   __attribute__((ext_vector_type(4)));
typedef unsigned short u16x4 __attribute__((ext_vector_type(4)));

__device__ inline unsigned short f2bf(float f) {
    unsigned u = __builtin_bit_cast(unsigned, f);
    u += 0x7fffu + ((u >> 16) & 1u);          // RNE
    return (unsigned short)(u >> 16);
}
__device__ inline int swz(int st) { return ((st ^ (st >> 4)) & 15) << 4; }

// ---------------------------------------------------------------------------
// Repack spatial weights -> frag-major bf16:
// wA[tap][co>>4][ci>>5][(ci>>3)&3][co&15][ci&7]
// so an A-frag load is one coalesced global_load_dwordx4 per lane.
// ---------------------------------------------------------------------------
__global__ void repack_wsp(const float* __restrict__ w, short* __restrict__ wA) {
    int s = blockIdx.x * 256 + threadIdx.x;
    if (s >= 128 * 128 * 9) return;
    int co = s / 1152, r = s % 1152, ci = r / 9, kh = (r % 9) / 3, kw = r % 3;
    int tap = kh * 3 + kw;
    int dst = tap * 16384 + (co >> 4) * 2048 + (ci >> 5) * 512 +
              ((ci >> 3) & 3) * 128 + (co & 15) * 8 + (ci & 7);
    wA[dst] = (short)f2bf(w[s]);
}

__global__ void repack_wt2(const float* __restrict__ w, short* __restrict__ wAt) {
    int s = blockIdx.x * 256 + threadIdx.x;
    if (s >= 128 * 128 * 3) return;
    int o = s / 384, r = s % 384, i = r / 3, tap = r % 3;
    int dst = tap * 16384 + (o >> 4) * 2048 + (i >> 5) * 512 +
              ((i >> 3) & 3) * 128 + (o & 15) * 8 + (i & 7);
    wAt[dst] = (short)f2bf(w[s]);
}

// ---------------------------------------------------------------------------
// Spatial 3x3 conv as 9 shifted MFMA GEMMs. Block = 2 waves (128 thr).
// Tile: 128 co x 112 px (4 rows). LDS: x window [170 st][128 ci] bf16,
// XOR-swizzled, staged once (rows h0-1..h0+4, zero rows for OOB, pad rows
// st=0/169 for masked-lane reads). Output: yT bf16 [t][px][ci] (+b_sp).
// ---------------------------------------------------------------------------
__global__ __launch_bounds__(128) void spatial_mfma(
    const float* __restrict__ x, const short* __restrict__ wA,
    const float* __restrict__ b_sp, unsigned short* __restrict__ yT)
{
    __shared__ __align__(16) short xs[170 * 128];
    const int t = blockIdx.y, h0 = blockIdx.x * 4;
    const int tid = threadIdx.x;

    // ---- stage: transpose fp32 [ci][px-window] -> LDS bf16 [st][ci] ----
    for (int it = 0; it < 21; ++it) {
        int u = it * 128 + tid;          // 64 ci-pairs x 42 float4-groups
        int cp = u / 42, pg = u % 42;
        int rl = pg / 7, g = pg % 7;
        int rr = h0 - 1 + rl;
        float4 f0 = make_float4(0.f, 0.f, 0.f, 0.f), f1 = f0;
        if (rr >= 0 && rr < 28) {
            const float* p0 = &x[((size_t)(t * CH + 2 * cp)) * HWP + rr * 28 + g * 4];
            f0 = *(const float4*)p0;
            f1 = *(const float4*)(p0 + HWP);
        }
        float a0[4] = {f0.x, f0.y, f0.z, f0.w}, a1[4] = {f1.x, f1.y, f1.z, f1.w};
#pragma unroll
        for (int j = 0; j < 4; ++j) {
            int st = 1 + pg * 4 + j;
            unsigned val = (unsigned)f2bf(a0[j]) | ((unsigned)f2bf(a1[j]) << 16);
            int addr = (st << 8) + (cp << 2);
            addr ^= swz(st);
            *(unsigned*)((char*)xs + addr) = val;
        }
    }
    __syncthreads();

    const int wm = tid >> 6, l = tid & 63;
    const int l15 = l & 15, kgrp = l >> 4;

    int st0[7], mL[7], mR[7];
#pragma unroll
    for (int nf = 0; nf < 7; ++nf) {
        int pl = nf * 16 + l15;
        st0[nf] = pl + 29;               // st for tap-offset 0
        int w28 = pl % 28;
        mL[nf] = (w28 != 0)  ? -1 : 0;   // kw=-1 valid
        mR[nf] = (w28 != 27) ? -1 : 0;   // kw=+1 valid
    }

    f32x4 acc[4][7];
#pragma unroll
    for (int m = 0; m < 4; ++m)
#pragma unroll
        for (int n = 0; n < 7; ++n) acc[m][n] = (f32x4){0.f, 0.f, 0.f, 0.f};

    const bf16x8* wAv = (const bf16x8*)wA;

    for (int tap = 0; tap < 9; ++tap) {
        int kh = tap / 3, kw = tap % 3;
        int off = (kh - 1) * 28 + (kw - 1);
#pragma unroll
        for (int ks = 0; ks < 4; ++ks) {
            bf16x8 a0 = wAv[((tap * 8 + wm * 4 + 0) * 4 + ks) * 64 + l];
            bf16x8 a1 = wAv[((tap * 8 + wm * 4 + 1) * 4 + ks) * 64 + l];
            bf16x8 a2 = wAv[((tap * 8 + wm * 4 + 2) * 4 + ks) * 64 + l];
            bf16x8 a3 = wAv[((tap * 8 + wm * 4 + 3) * 4 + ks) * 64 + l];
#pragma unroll
            for (int nf = 0; nf < 7; ++nf) {
                int st = st0[nf] + off;
                int addr = (st << 8) + (ks << 6) + (kgrp << 4);
                addr ^= swz(st);
                i32x4 bi = *(const i32x4*)((const char*)xs + addr);
                int msk = (kw == 0) ? mL[nf] : ((kw == 2) ? mR[nf] : -1);
                bi = bi & msk;
                bf16x8 b = __builtin_bit_cast(bf16x8, bi);
                acc[0][nf] = __builtin_amdgcn_mfma_f32_16x16x32_bf16(a0, b, acc[0][nf], 0, 0, 0);
                acc[1][nf] = __builtin_amdgcn_mfma_f32_16x16x32_bf16(a1, b, acc[1][nf], 0, 0, 0);
                acc[2][nf] = __builtin_amdgcn_mfma_f32_16x16x32_bf16(a2, b, acc[2][nf], 0, 0, 0);
                acc[3][nf] = __builtin_amdgcn_mfma_f32_16x16x32_bf16(a3, b, acc[3][nf], 0, 0, 0);
            }
        }
    }

    // ---- epilogue: +b_sp, pack 4 consecutive co as bf16, store yT ----
#pragma unroll
    for (int m = 0; m < 4; ++m) {
        int cob = wm * 64 + m * 16 + kgrp * 4;
        float4 bs = *(const float4*)&b_sp[cob];
        float bsa[4] = {bs.x, bs.y, bs.z, bs.w};
#pragma unroll
        for (int nf = 0; nf < 7; ++nf) {
            int px = h0 * 28 + nf * 16 + l15;
            u16x4 pk;
#pragma unroll
            for (int r = 0; r < 4; ++r) pk[r] = f2bf(acc[m][nf][r] + bsa[r]);
            *(u16x4*)&yT[((size_t)t * HWP + px) * CH + cob] = pk;
        }
    }
}

// ---------------------------------------------------------------------------
// Ragged temporal conv (k=3) as 3 shifted MFMA GEMMs + bias + PReLU +
// residual. No LDS: B-frags straight from global yT (L2-hot, full-line use).
// Wave = 64 co x 112 px; 4 independent waves per block.
// ---------------------------------------------------------------------------
__global__ __launch_bounds__(256) void temporal_mfma(
    const unsigned short* __restrict__ yT, const short* __restrict__ wAt,
    const float* __restrict__ b_t, const float* __restrict__ alpha,
    const float* __restrict__ x, const int* __restrict__ vid_lens,
    float* __restrict__ out)
{
    const int tid = threadIdx.x, wid = tid >> 6, l = tid & 63;
    const int l15 = l & 15, kgrp = l >> 4;
    int wu = blockIdx.x * 4 + wid;          // 512*14 wave-units
    int t = wu / 14, r = wu % 14, wm = r & 1, chunk = r >> 1;

    bool isS = false, isE = false;
    {
        int cum = 0;
        for (int s = 0; s < NSEG; ++s) {
            if (t == cum) isS = true;
            cum += vid_lens[s];
            if (t == cum - 1) isE = true;
        }
    }

    f32x4 acc[4][7];
#pragma unroll
    for (int m = 0; m < 4; ++m)
#pragma unroll
        for (int n = 0; n < 7; ++n) acc[m][n] = (f32x4){0.f, 0.f, 0.f, 0.f};

    const bf16x8* wAv = (const bf16x8*)wAt;

    for (int tap = 0; tap < 3; ++tap) {
        if (tap == 0 && isS) continue;      // zero contribution at segment start
        if (tap == 2 && isE) continue;      // zero contribution at segment end
        int tp = t + tap - 1;
        const unsigned short* yb = yT + (size_t)tp * HWP * CH;
#pragma unroll
        for (int ks = 0; ks < 4; ++ks) {
            bf16x8 a0 = wAv[((tap * 8 + wm * 4 + 0) * 4 + ks) * 64 + l];
            bf16x8 a1 = wAv[((tap * 8 + wm * 4 + 1) * 4 + ks) * 64 + l];
            bf16x8 a2 = wAv[((tap * 8 + wm * 4 + 2) * 4 + ks) * 64 + l];
            bf16x8 a3 = wAv[((tap * 8 + wm * 4 + 3) * 4 + ks) * 64 + l];
#pragma unroll
            for (int nf = 0; nf < 7; ++nf) {
                int px = chunk * 112 + nf * 16 + l15;
                bf16x8 b = *(const bf16x8*)&yb[(size_t)px * CH + ks * 32 + kgrp * 8];
                acc[0][nf] = __builtin_amdgcn_mfma_f32_16x16x32_bf16(a0, b, acc[0][nf], 0, 0, 0);
                acc[1][nf] = __builtin_amdgcn_mfma_f32_16x16x32_bf16(a1, b, acc[1][nf], 0, 0, 0);
                acc[2][nf] = __builtin_amdgcn_mfma_f32_16x16x32_bf16(a2, b, acc[2][nf], 0, 0, 0);
                acc[3][nf] = __builtin_amdgcn_mfma_f32_16x16x32_bf16(a3, b, acc[3][nf], 0, 0, 0);
            }
        }
    }

    // ---- epilogue: +b_t, PReLU, +x residual, store fp32 ----
#pragma unroll
    for (int m = 0; m < 4; ++m) {
        int cob = wm * 64 + m * 16 + kgrp * 4;
        float4 bt = *(const float4*)&b_t[cob];
        float4 al = *(const float4*)&alpha[cob];
        float bta[4] = {bt.x, bt.y, bt.z, bt.w};
        float ala[4] = {al.x, al.y, al.z, al.w};
#pragma unroll
        for (int nf = 0; nf < 7; ++nf) {
            int px = chunk * 112 + nf * 16 + l15;
#pragma unroll
            for (int rr = 0; rr < 4; ++rr) {
                size_t idx = ((size_t)(t * CH + cob + rr)) * HWP + px;
                float v = acc[m][nf][rr] + bta[rr];
                v = (v >= 0.f) ? v : ala[rr] * v;
                out[idx] = v + x[idx];
            }
        }
    }
}

// ---------------------------------------------------------------------------
__global__ void write_lens(const int* __restrict__ vid_lens, float* __restrict__ out) {
    int i = threadIdx.x;
    if (i < NSEG) out[NOUT + i] = (float)vid_lens[i];
}

// ---------------------------------------------------------------------------
extern "C" void kernel_launch(void* const* d_in, const int* in_sizes, int n_in,
                              void* d_out, int out_size, void* d_ws, size_t ws_size,
                              hipStream_t stream) {
    const float* x        = (const float*)d_in[0];
    const int*   vid_lens = (const int*)d_in[1];
    const float* w_sp     = (const float*)d_in[2];
    const float* b_sp     = (const float*)d_in[3];
    const float* w_t      = (const float*)d_in[4];
    const float* b_t      = (const float*)d_in[5];
    const float* alpha    = (const float*)d_in[6];
    float* out = (float*)d_out;

    unsigned short* yT = (unsigned short*)d_ws;                       // 102,760,448 B
    short* wA  = (short*)((char*)d_ws + 102760448);                   //    294,912 B
    short* wAt = (short*)((char*)d_ws + 102760448 + 294912);          //     98,304 B

    repack_wsp<<<576, 256, 0, stream>>>(w_sp, wA);
    repack_wt2<<<192, 256, 0, stream>>>(w_t, wAt);
    spatial_mfma<<<dim3(7, 512), 128, 0, stream>>>(x, wA, b_sp, yT);
    temporal_mfma<<<1792, 256, 0, stream>>>(yT, wAt, b_t, alpha, x, vid_lens, out);
    write_lens<<<1, 64, 0, stream>>>(vid_lens, out);
}

// Round 3
// 332.642 us; speedup vs baseline: 9.8153x; 2.3525x over previous
//
#include <hip/hip_runtime.h>

#define TT   512
#define CH   128
#define HWP  784        // 28*28
#define NSEG 8
#define NOUT 51380224   // 512*128*784

typedef short bf16x8  __attribute__((ext_vector_type(8)));
typedef float f32x4   __attribute__((ext_vector_type(4)));
typedef int   i32x4   __attribute__((ext_vector_type(4)));
typedef unsigned short u16x4 __attribute__((ext_vector_type(4)));

__device__ inline unsigned short f2bf(float f) {
    unsigned u = __builtin_bit_cast(unsigned, f);
    u += 0x7fffu + ((u >> 16) & 1u);          // RNE
    return (unsigned short)(u >> 16);
}
__device__ inline int swz(int st) { return ((st ^ (st >> 4)) & 15) << 4; }

__device__ inline void gld_lds16(const void* g, void* l) {
    __builtin_amdgcn_global_load_lds(
        (const __attribute__((address_space(1))) void*)g,
        (__attribute__((address_space(3))) void*)l, 16, 0, 0);
}

// ---------------------------------------------------------------------------
// Repack weights -> frag-major bf16: wA[tap][co>>4][ci>>5][(ci>>3)&3][co&15][ci&7]
// ---------------------------------------------------------------------------
__global__ void repack_wsp(const float* __restrict__ w, short* __restrict__ wA) {
    int s = blockIdx.x * 256 + threadIdx.x;
    if (s >= 128 * 128 * 9) return;
    int co = s / 1152, r = s % 1152, ci = r / 9, kh = (r % 9) / 3, kw = r % 3;
    int tap = kh * 3 + kw;
    int dst = tap * 16384 + (co >> 4) * 2048 + (ci >> 5) * 512 +
              ((ci >> 3) & 3) * 128 + (co & 15) * 8 + (ci & 7);
    wA[dst] = (short)f2bf(w[s]);
}

__global__ void repack_wt2(const float* __restrict__ w, short* __restrict__ wAt) {
    int s = blockIdx.x * 256 + threadIdx.x;
    if (s >= 128 * 128 * 3) return;
    int o = s / 384, r = s % 384, i = r / 3, tap = r % 3;
    int dst = tap * 16384 + (o >> 4) * 2048 + (i >> 5) * 512 +
              ((i >> 3) & 3) * 128 + (o & 15) * 8 + (i & 7);
    wAt[dst] = (short)f2bf(w[s]);
}

// ---------------------------------------------------------------------------
// Spatial 3x3 conv, 8-wave blocks. grid (4, 512), block 512.
// Block: 8 output rows (last block 4), 128 co. Window: 10 rows in LDS,
// bf16 [st][ci], XOR-swizzled. Waves: wm(co half) x rg(row group) x nfh(px half).
// ---------------------------------------------------------------------------
__global__ __launch_bounds__(512, 4) void spatial_mfma(
    const float* __restrict__ x, const short* __restrict__ wA,
    const float* __restrict__ b_sp, unsigned short* __restrict__ yT)
{
    __shared__ __align__(16) short xs[282 * 128];   // 72192 B
    const int t = blockIdx.y, blockh = blockIdx.x * 8;
    const int tid = threadIdx.x;

    // ---- stage: transpose fp32 [ci][px-window(10 rows)] -> LDS bf16 [st][ci]
    for (int it = 0; it < 9; ++it) {
        int u = it * 512 + tid;              // 64 ci-pairs x 70 float4-groups
        if (u < 4480) {
            int cp = u / 70, pg = u % 70;
            int rl = pg / 7, g = pg % 7;
            int rr = blockh - 1 + rl;
            float4 f0 = make_float4(0.f, 0.f, 0.f, 0.f), f1 = f0;
            if (rr >= 0 && rr < 28) {
                const float* p0 = &x[((size_t)(t * CH + 2 * cp)) * HWP + rr * 28 + g * 4];
                f0 = *(const float4*)p0;
                f1 = *(const float4*)(p0 + HWP);
            }
            float a0[4] = {f0.x, f0.y, f0.z, f0.w}, a1[4] = {f1.x, f1.y, f1.z, f1.w};
#pragma unroll
            for (int j = 0; j < 4; ++j) {
                int st = 1 + pg * 4 + j;
                unsigned val = (unsigned)f2bf(a0[j]) | ((unsigned)f2bf(a1[j]) << 16);
                int addr = (st << 8) + (cp << 2);
                addr ^= swz(st);
                *(unsigned*)((char*)xs + addr) = val;
            }
        }
    }
    __syncthreads();

    const int wid = tid >> 6, l = tid & 63;
    const int wm = wid & 1, rg = (wid >> 1) & 1, nfh = wid >> 2;
    const int l15 = l & 15, kgrp = l >> 4;
    const int h0 = blockh + rg * 4;
    if (h0 >= 28) return;                    // block 3, rg=1: no rows (after sync)

    int st0[4], mL[4], mR[4];
#pragma unroll
    for (int nfi = 0; nfi < 4; ++nfi) {
        int pl = (nfh * 4 + nfi) * 16 + l15;         // px within 112-tile
        int plc = (pl < 112) ? pl : 0;               // clamp nf==7 (garbage lane)
        st0[nfi] = plc + 29 + rg * 112;
        int w28 = plc % 28;
        mL[nfi] = (w28 != 0)  ? -1 : 0;
        mR[nfi] = (w28 != 27) ? -1 : 0;
    }

    f32x4 acc[4][4];
#pragma unroll
    for (int m = 0; m < 4; ++m)
#pragma unroll
        for (int n = 0; n < 4; ++n) acc[m][n] = (f32x4){0.f, 0.f, 0.f, 0.f};

    const bf16x8* wAv = (const bf16x8*)wA;

    for (int tap = 0; tap < 9; ++tap) {
        int kh = tap / 3, kw = tap % 3;
        int off = (kh - 1) * 28 + (kw - 1);
#pragma unroll
        for (int ks = 0; ks < 4; ++ks) {
            bf16x8 a0 = wAv[((tap * 8 + wm * 4 + 0) * 4 + ks) * 64 + l];
            bf16x8 a1 = wAv[((tap * 8 + wm * 4 + 1) * 4 + ks) * 64 + l];
            bf16x8 a2 = wAv[((tap * 8 + wm * 4 + 2) * 4 + ks) * 64 + l];
            bf16x8 a3 = wAv[((tap * 8 + wm * 4 + 3) * 4 + ks) * 64 + l];
#pragma unroll
            for (int nfi = 0; nfi < 4; ++nfi) {
                int st = st0[nfi] + off;
                int addr = (st << 8) + (ks << 6) + (kgrp << 4);
                addr ^= swz(st);
                i32x4 bi = *(const i32x4*)((const char*)xs + addr);
                int msk = (kw == 0) ? mL[nfi] : ((kw == 2) ? mR[nfi] : -1);
                bi = bi & msk;
                bf16x8 b = __builtin_bit_cast(bf16x8, bi);
                acc[0][nfi] = __builtin_amdgcn_mfma_f32_16x16x32_bf16(a0, b, acc[0][nfi], 0, 0, 0);
                acc[1][nfi] = __builtin_amdgcn_mfma_f32_16x16x32_bf16(a1, b, acc[1][nfi], 0, 0, 0);
                acc[2][nfi] = __builtin_amdgcn_mfma_f32_16x16x32_bf16(a2, b, acc[2][nfi], 0, 0, 0);
                acc[3][nfi] = __builtin_amdgcn_mfma_f32_16x16x32_bf16(a3, b, acc[3][nfi], 0, 0, 0);
            }
        }
    }

    // ---- epilogue: +b_sp, pack 4 co as bf16, store yT [t][px][ci] ----
#pragma unroll
    for (int m = 0; m < 4; ++m) {
        int cob = wm * 64 + m * 16 + kgrp * 4;
        float4 bs = *(const float4*)&b_sp[cob];
        float bsa[4] = {bs.x, bs.y, bs.z, bs.w};
#pragma unroll
        for (int nfi = 0; nfi < 4; ++nfi) {
            int pl = (nfh * 4 + nfi) * 16 + l15;
            if (nfh == 1 && nfi == 3) continue;      // nf==7 garbage
            int px = h0 * 28 + pl;
            u16x4 pk;
#pragma unroll
            for (int r = 0; r < 4; ++r) pk[r] = f2bf(acc[m][nfi][r] + bsa[r]);
            *(u16x4*)&yT[((size_t)t * HWP + px) * CH + cob] = pk;
        }
    }
}

// ---------------------------------------------------------------------------
// Ragged temporal conv: 4-wave blocks, async LDS-staged B, double-buffered.
// grid (7, 512), block 256. Block: frame t, 112 px, 128 co (32/wave).
// Stage s = (tap, kspair): tile [112px][64ci] bf16, slot-XOR swizzle via
// pre-swizzled global source. Epilogue: LDS transpose -> float4 x/out.
// ---------------------------------------------------------------------------
__global__ __launch_bounds__(256, 4) void temporal_mfma(
    const unsigned short* __restrict__ yT, const short* __restrict__ wAt,
    const float* __restrict__ b_t, const float* __restrict__ alpha,
    const float* __restrict__ x, const int* __restrict__ vid_lens,
    float* __restrict__ out)
{
    __shared__ __align__(16) char ldsT[29696];   // 2x14336 stage | 4x7424 epi

    const int chunk = blockIdx.x, t = blockIdx.y;
    const int tid = threadIdx.x, wid = tid >> 6, l = tid & 63;
    const int l15 = l & 15, kgrp = l >> 4;
    const int sx = l15 & 7;

    bool isS = false, isE = false;
    {
        int cum = 0;
        for (int s = 0; s < NSEG; ++s) {
            if (t == cum) isS = true;
            cum += vid_lens[s];
            if (t == cum - 1) isE = true;
        }
    }
    const bool tapAct[3] = {!isS, true, !isE};

    // stage s: tap = s>>1, kp = s&1 -> buf[s&1]
    auto stage = [&](int s) {
        int tap = s >> 1, kp = s & 1;
        if (!tapAct[tap]) return;
        int tp = t + tap - 1;
        const char* yb = (const char*)yT + (size_t)tp * HWP * 256;
        char* buf = ldsT + (s & 1) * 14336;
#pragma unroll
        for (int r = 0; r < 4; ++r) {
            int c = r * 256 + wid * 64 + l;
            if (r < 3 || wid < 2) {                    // c < 896, wave-uniform
                int px = c >> 3, sp = c & 7;
                int ssrc = sp ^ (px & 7);
                const char* g = yb + ((size_t)(chunk * 112 + px)) * 256 + kp * 128 + ssrc * 16;
                char* ldst = buf + (r * 256 + wid * 64) * 16;
                gld_lds16(g, ldst);
            }
        }
    };

    f32x4 acc[2][7];
#pragma unroll
    for (int m = 0; m < 2; ++m)
#pragma unroll
        for (int n = 0; n < 7; ++n) acc[m][n] = (f32x4){0.f, 0.f, 0.f, 0.f};

    const bf16x8* wAv = (const bf16x8*)wAt;

    stage(0);
    __syncthreads();

    for (int s = 0; s < 6; ++s) {
        if (s < 5) stage(s + 1);
        int tap = s >> 1, kp = s & 1;
        if (tapAct[tap]) {
            const char* buf = ldsT + (s & 1) * 14336;
            bf16x8 a[2][2];
#pragma unroll
            for (int m = 0; m < 2; ++m)
#pragma unroll
                for (int k1 = 0; k1 < 2; ++k1)
                    a[m][k1] = wAv[((tap * 8 + wid * 2 + m) * 4 + kp * 2 + k1) * 64 + l];
#pragma unroll
            for (int k1 = 0; k1 < 2; ++k1) {
#pragma unroll
                for (int nf = 0; nf < 7; ++nf) {
                    int addr = (nf * 16 + l15) * 128 + ((k1 * 4 + kgrp) ^ sx) * 16;
                    i32x4 bi = *(const i32x4*)(buf + addr);
                    bf16x8 b = __builtin_bit_cast(bf16x8, bi);
                    acc[0][nf] = __builtin_amdgcn_mfma_f32_16x16x32_bf16(a[0][k1], b, acc[0][nf], 0, 0, 0);
                    acc[1][nf] = __builtin_amdgcn_mfma_f32_16x16x32_bf16(a[1][k1], b, acc[1][nf], 0, 0, 0);
                }
            }
        }
        __syncthreads();
    }

    // ---- epilogue: LDS transpose -> coalesced bias/PReLU/residual/store ----
    float* fl = (float*)ldsT;
    const int wbase = wid * 1856;            // 16 co x 116 px-stride floats
#pragma unroll
    for (int m = 0; m < 2; ++m) {
#pragma unroll
        for (int nf = 0; nf < 7; ++nf)
#pragma unroll
            for (int rr = 0; rr < 4; ++rr)
                fl[wbase + (kgrp * 4 + rr) * 116 + nf * 16 + l15] = acc[m][nf][rr];
        // wave-private region; compiler inserts lgkmcnt before dependent reads
#pragma unroll
        for (int j = 0; j < 7; ++j) {
            int idx = j * 64 + l;
            int co_r = idx / 28, q = idx % 28;
            f32x4 v4 = *(const f32x4*)&fl[wbase + co_r * 116 + q * 4];
            int co_g = wid * 32 + m * 16 + co_r;
            float bt = b_t[co_g], al = alpha[co_g];
            size_t gi = ((size_t)(t * CH + co_g)) * HWP + chunk * 112 + q * 4;
            float4 xv = *(const float4*)&x[gi];
            float xr[4] = {xv.x, xv.y, xv.z, xv.w};
            float rrv[4];
#pragma unroll
            for (int e = 0; e < 4; ++e) {
                float v = v4[e] + bt;
                v = (v >= 0.f) ? v : al * v;
                rrv[e] = v + xr[e];
            }
            *(float4*)&out[gi] = make_float4(rrv[0], rrv[1], rrv[2], rrv[3]);
        }
        __syncthreads();   // all waves done with region before m=1 reuse
    }
}

// ---------------------------------------------------------------------------
__global__ void write_lens(const int* __restrict__ vid_lens, float* __restrict__ out) {
    int i = threadIdx.x;
    if (i < NSEG) out[NOUT + i] = (float)vid_lens[i];
}

// ---------------------------------------------------------------------------
extern "C" void kernel_launch(void* const* d_in, const int* in_sizes, int n_in,
                              void* d_out, int out_size, void* d_ws, size_t ws_size,
                              hipStream_t stream) {
    const float* x        = (const float*)d_in[0];
    const int*   vid_lens = (const int*)d_in[1];
    const float* w_sp     = (const float*)d_in[2];
    const float* b_sp     = (const float*)d_in[3];
    const float* w_t      = (const float*)d_in[4];
    const float* b_t      = (const float*)d_in[5];
    const float* alpha    = (const float*)d_in[6];
    float* out = (float*)d_out;

    unsigned short* yT = (unsigned short*)d_ws;                       // 102,760,448 B
    short* wA  = (short*)((char*)d_ws + 102760448);                   //    294,912 B
    short* wAt = (short*)((char*)d_ws + 102760448 + 294912);          //     98,304 B

    repack_wsp<<<576, 256, 0, stream>>>(w_sp, wA);
    repack_wt2<<<192, 256, 0, stream>>>(w_t, wAt);
    spatial_mfma<<<dim3(4, 512), 512, 0, stream>>>(x, wA, b_sp, yT);
    temporal_mfma<<<dim3(7, 512), 256, 0, stream>>>(yT, wAt, b_t, alpha, x, vid_lens, out);
    write_lens<<<1, 64, 0, stream>>>(vid_lens, out);
}

// Round 4
// 297.744 us; speedup vs baseline: 10.9658x; 1.1172x over previous
//
#include <hip/hip_runtime.h>

#define TT   512
#define CH   128
#define HWP  784        // 28*28
#define NSEG 8
#define NOUT 51380224   // 512*128*784

typedef short bf16x8  __attribute__((ext_vector_type(8)));
typedef float f32x4   __attribute__((ext_vector_type(4)));
typedef int   i32x4   __attribute__((ext_vector_type(4)));
typedef unsigned short u16x8 __attribute__((ext_vector_type(8)));

__device__ inline unsigned short f2bf(float f) {
    unsigned u = __builtin_bit_cast(unsigned, f);
    u += 0x7fffu + ((u >> 16) & 1u);          // RNE
    return (unsigned short)(u >> 16);
}

__device__ inline void gld_lds16(const void* g, void* l) {
    __builtin_amdgcn_global_load_lds(
        (const __attribute__((address_space(1))) void*)g,
        (__attribute__((address_space(3))) void*)l, 16, 0, 0);
}

// ---------------------------------------------------------------------------
// Repack spatial weights -> frag-major bf16 (identity ci<->k mapping):
// wA[tap][co>>4][ci>>5][(ci>>3)&3][co&15][ci&7]
// ---------------------------------------------------------------------------
__global__ void repack_wsp(const float* __restrict__ w, short* __restrict__ wA) {
    int s = blockIdx.x * 256 + threadIdx.x;
    if (s >= 128 * 128 * 9) return;
    int co = s / 1152, r = s % 1152, ci = r / 9, kh = (r % 9) / 3, kw = r % 3;
    int tap = kh * 3 + kw;
    int dst = tap * 16384 + (co >> 4) * 2048 + (ci >> 5) * 512 +
              ((ci >> 3) & 3) * 128 + (co & 15) * 8 + (ci & 7);
    wA[dst] = (short)f2bf(w[s]);
}

// ---------------------------------------------------------------------------
// Temporal weight repack. yT stores channels PERMUTED (spatial's store-
// friendly order): stored position k holds channel
//   ci(k) = (k&96) + ((k>>2)&1)*16 + ((k>>3)&3)*4 + (k&3)
// so the temporal A-frag picks the matching channel for each k-position.
// ---------------------------------------------------------------------------
__global__ void repack_wt2(const float* __restrict__ w, short* __restrict__ wAt) {
    int s = blockIdx.x * 256 + threadIdx.x;
    if (s >= 128 * 128 * 3) return;
    int o = s / 384, r = s % 384, k = r / 3, tap = r % 3;
    int ci = (k & 96) | (((k >> 2) & 1) << 4) | (((k >> 3) & 3) << 2) | (k & 3);
    int dst = tap * 16384 + (o >> 4) * 2048 + (k >> 5) * 512 +
              ((k >> 3) & 3) * 128 + (o & 15) * 8 + (k & 7);
    wAt[dst] = (short)f2bf(w[o * 384 + ci * 3 + tap]);
}

// ---------------------------------------------------------------------------
// Spatial 3x3 conv, 8-wave blocks. grid (4, 512), block 512.
// LDS: zero-padded window [10 rows][30 wp][128 ci] bf16, st = row*30+w+1,
// XOR-swizzled. No masks needed: kw shifts land on zero pad columns.
// Waves: wm(co half) x rg(row group of 4) x ms(m-pair). Per wave: 2m x 7nf.
// Output: yT bf16 [t][px][128 perm-ci], full-64B-line u16x8 stores.
// ---------------------------------------------------------------------------
__global__ __launch_bounds__(512, 4) void spatial_mfma(
    const float* __restrict__ x, const short* __restrict__ wA,
    const float* __restrict__ b_sp, unsigned short* __restrict__ yT)
{
    __shared__ __align__(16) short xs[300 * 128];   // 76800 B
    char* xsb = (char*)xs;
    const int t = blockIdx.y, blockh = blockIdx.x * 8;
    const int tid = threadIdx.x;

    // ---- zero pad columns: st = rl*30 + {0,29} ----
    for (int it = 0; it < 3; ++it) {
        int u = it * 512 + tid;
        if (u < 1280) {
            int cp = u & 63, rs = u >> 6;        // rs 0..19
            int st = (rs >> 1) * 30 + (rs & 1) * 29;
            int addr = (st << 8) | (cp << 2);
            addr ^= ((st ^ (st >> 4)) & 15) << 4;
            *(unsigned*)(xsb + addr) = 0u;
        }
    }
    // ---- stage x window: lane=cp (conflict-free writes), wave-uniform st ----
    for (int it = 0; it < 9; ++it) {
        int u = it * 512 + tid;
        if (u < 4480) {
            int cp = u & 63, pq = u >> 6;        // pq 0..69
            int rl = pq / 7, g = pq % 7;
            int rr = blockh - 1 + rl;
            float4 f0 = make_float4(0.f, 0.f, 0.f, 0.f), f1 = f0;
            if (rr >= 0 && rr < 28) {
                const float* p0 = &x[((size_t)(t * CH + 2 * cp)) * HWP + rr * 28 + g * 4];
                f0 = *(const float4*)p0;
                f1 = *(const float4*)(p0 + HWP);
            }
            float a0[4] = {f0.x, f0.y, f0.z, f0.w}, a1[4] = {f1.x, f1.y, f1.z, f1.w};
            int stb = rl * 30 + g * 4 + 1;
#pragma unroll
            for (int j = 0; j < 4; ++j) {
                int st = stb + j;
                unsigned val = (unsigned)f2bf(a0[j]) | ((unsigned)f2bf(a1[j]) << 16);
                int addr = (st << 8) | (cp << 2);
                addr ^= ((st ^ (st >> 4)) & 15) << 4;
                *(unsigned*)(xsb + addr) = val;
            }
        }
    }
    __syncthreads();

    const int wid = tid >> 6, l = tid & 63;
    const int wm = wid & 1, rg = (wid >> 1) & 1, ms = wid >> 2;
    const int l15 = l & 15, kgrp = l >> 4;
    const int h0 = blockh + rg * 4;
    if (h0 >= 28) return;                        // block 3, rg=1: nothing to do

    int st0[7];
#pragma unroll
    for (int nf = 0; nf < 7; ++nf) {
        int pl = nf * 16 + l15;                  // 0..111
        st0[nf] = (rg * 4 + pl / 28 + 1) * 30 + (pl % 28) + 1;
    }

    f32x4 acc[2][7];
#pragma unroll
    for (int d = 0; d < 2; ++d)
#pragma unroll
        for (int n = 0; n < 7; ++n) acc[d][n] = (f32x4){0.f, 0.f, 0.f, 0.f};

    const bf16x8* wAv = (const bf16x8*)wA;

    for (int tap = 0; tap < 9; ++tap) {
        int off = (tap / 3 - 1) * 30 + (tap % 3 - 1);
        int adr[7];
#pragma unroll
        for (int nf = 0; nf < 7; ++nf) {
            int st = st0[nf] + off;
            adr[nf] = ((st << 8) | (kgrp << 4)) ^ (((st ^ (st >> 4)) & 15) << 4);
        }
#pragma unroll
        for (int ks = 0; ks < 4; ++ks) {
            bf16x8 a0 = wAv[((tap * 8 + wm * 4 + ms * 2 + 0) * 4 + ks) * 64 + l];
            bf16x8 a1 = wAv[((tap * 8 + wm * 4 + ms * 2 + 1) * 4 + ks) * 64 + l];
            __builtin_amdgcn_s_setprio(1);
#pragma unroll
            for (int nf = 0; nf < 7; ++nf) {
                i32x4 bi = *(const i32x4*)(xsb + (adr[nf] ^ (ks << 6)));
                bf16x8 b = __builtin_bit_cast(bf16x8, bi);
                acc[0][nf] = __builtin_amdgcn_mfma_f32_16x16x32_bf16(a0, b, acc[0][nf], 0, 0, 0);
                acc[1][nf] = __builtin_amdgcn_mfma_f32_16x16x32_bf16(a1, b, acc[1][nf], 0, 0, 0);
            }
            __builtin_amdgcn_s_setprio(0);
        }
    }

    // ---- epilogue: +b_sp, u16x8 (m-pair) stores -> full 64B lines ----
    float4 blo = *(const float4*)&b_sp[wm * 64 + ms * 32 + kgrp * 4];
    float4 bhi = *(const float4*)&b_sp[wm * 64 + ms * 32 + 16 + kgrp * 4];
    float bl[4] = {blo.x, blo.y, blo.z, blo.w}, bh[4] = {bhi.x, bhi.y, bhi.z, bhi.w};
#pragma unroll
    for (int nf = 0; nf < 7; ++nf) {
        int px = h0 * 28 + nf * 16 + l15;
        u16x8 pk;
#pragma unroll
        for (int r = 0; r < 4; ++r) {
            pk[r]     = f2bf(acc[0][nf][r] + bl[r]);
            pk[4 + r] = f2bf(acc[1][nf][r] + bh[r]);
        }
        char* dst = (char*)yT + ((size_t)t * HWP + px) * 256 + wm * 128 + ms * 64 + kgrp * 16;
        *(u16x8*)dst = pk;
    }
}

// ---------------------------------------------------------------------------
// Ragged temporal conv: 4-wave blocks, async LDS-staged B, double-buffered.
// grid (7, 512), block 256. (yT channel permutation absorbed by wAt repack.)
// ---------------------------------------------------------------------------
__global__ __launch_bounds__(256, 4) void temporal_mfma(
    const unsigned short* __restrict__ yT, const short* __restrict__ wAt,
    const float* __restrict__ b_t, const float* __restrict__ alpha,
    const float* __restrict__ x, const int* __restrict__ vid_lens,
    float* __restrict__ out)
{
    __shared__ __align__(16) char ldsT[29696];   // 2x14336 stage | 4x7424 epi

    const int chunk = blockIdx.x, t = blockIdx.y;
    const int tid = threadIdx.x, wid = tid >> 6, l = tid & 63;
    const int l15 = l & 15, kgrp = l >> 4;
    const int sx = l15 & 7;

    bool isS = false, isE = false;
    {
        int cum = 0;
        for (int s = 0; s < NSEG; ++s) {
            if (t == cum) isS = true;
            cum += vid_lens[s];
            if (t == cum - 1) isE = true;
        }
    }
    const bool tapAct[3] = {!isS, true, !isE};

    auto stage = [&](int s) {
        int tap = s >> 1, kp = s & 1;
        if (!tapAct[tap]) return;
        int tp = t + tap - 1;
        const char* yb = (const char*)yT + (size_t)tp * HWP * 256;
        char* buf = ldsT + (s & 1) * 14336;
#pragma unroll
        for (int r = 0; r < 4; ++r) {
            int c = r * 256 + wid * 64 + l;
            if (r < 3 || wid < 2) {                    // c < 896, wave-uniform
                int px = c >> 3, sp = c & 7;
                int ssrc = sp ^ (px & 7);
                const char* g = yb + ((size_t)(chunk * 112 + px)) * 256 + kp * 128 + ssrc * 16;
                char* ldst = buf + (r * 256 + wid * 64) * 16;
                gld_lds16(g, ldst);
            }
        }
    };

    f32x4 acc[2][7];
#pragma unroll
    for (int m = 0; m < 2; ++m)
#pragma unroll
        for (int n = 0; n < 7; ++n) acc[m][n] = (f32x4){0.f, 0.f, 0.f, 0.f};

    const bf16x8* wAv = (const bf16x8*)wAt;

    stage(0);
    __syncthreads();

    for (int s = 0; s < 6; ++s) {
        if (s < 5) stage(s + 1);
        int tap = s >> 1, kp = s & 1;
        if (tapAct[tap]) {
            const char* buf = ldsT + (s & 1) * 14336;
            bf16x8 a[2][2];
#pragma unroll
            for (int m = 0; m < 2; ++m)
#pragma unroll
                for (int k1 = 0; k1 < 2; ++k1)
                    a[m][k1] = wAv[((tap * 8 + wid * 2 + m) * 4 + kp * 2 + k1) * 64 + l];
            __builtin_amdgcn_s_setprio(1);
#pragma unroll
            for (int k1 = 0; k1 < 2; ++k1) {
#pragma unroll
                for (int nf = 0; nf < 7; ++nf) {
                    int addr = (nf * 16 + l15) * 128 + ((k1 * 4 + kgrp) ^ sx) * 16;
                    i32x4 bi = *(const i32x4*)(buf + addr);
                    bf16x8 b = __builtin_bit_cast(bf16x8, bi);
                    acc[0][nf] = __builtin_amdgcn_mfma_f32_16x16x32_bf16(a[0][k1], b, acc[0][nf], 0, 0, 0);
                    acc[1][nf] = __builtin_amdgcn_mfma_f32_16x16x32_bf16(a[1][k1], b, acc[1][nf], 0, 0, 0);
                }
            }
            __builtin_amdgcn_s_setprio(0);
        }
        __syncthreads();
    }

    // ---- epilogue: LDS transpose -> coalesced bias/PReLU/residual/store ----
    float* fl = (float*)ldsT;
    const int wbase = wid * 1856;            // 16 co x 116 px-stride floats
#pragma unroll
    for (int m = 0; m < 2; ++m) {
#pragma unroll
        for (int nf = 0; nf < 7; ++nf)
#pragma unroll
            for (int rr = 0; rr < 4; ++rr)
                fl[wbase + (kgrp * 4 + rr) * 116 + nf * 16 + l15] = acc[m][nf][rr];
#pragma unroll
        for (int j = 0; j < 7; ++j) {
            int idx = j * 64 + l;
            int co_r = idx / 28, q = idx % 28;
            f32x4 v4 = *(const f32x4*)&fl[wbase + co_r * 116 + q * 4];
            int co_g = wid * 32 + m * 16 + co_r;
            float bt = b_t[co_g], al = alpha[co_g];
            size_t gi = ((size_t)(t * CH + co_g)) * HWP + chunk * 112 + q * 4;
            float4 xv = *(const float4*)&x[gi];
            float xr[4] = {xv.x, xv.y, xv.z, xv.w};
            float rrv[4];
#pragma unroll
            for (int e = 0; e < 4; ++e) {
                float v = v4[e] + bt;
                v = (v >= 0.f) ? v : al * v;
                rrv[e] = v + xr[e];
            }
            *(float4*)&out[gi] = make_float4(rrv[0], rrv[1], rrv[2], rrv[3]);
        }
        __syncthreads();   // all waves done with region before m=1 reuse
    }
}

// ---------------------------------------------------------------------------
__global__ void write_lens(const int* __restrict__ vid_lens, float* __restrict__ out) {
    int i = threadIdx.x;
    if (i < NSEG) out[NOUT + i] = (float)vid_lens[i];
}

// ---------------------------------------------------------------------------
extern "C" void kernel_launch(void* const* d_in, const int* in_sizes, int n_in,
                              void* d_out, int out_size, void* d_ws, size_t ws_size,
                              hipStream_t stream) {
    const float* x        = (const float*)d_in[0];
    const int*   vid_lens = (const int*)d_in[1];
    const float* w_sp     = (const float*)d_in[2];
    const float* b_sp     = (const float*)d_in[3];
    const float* w_t      = (const float*)d_in[4];
    const float* b_t      = (const float*)d_in[5];
    const float* alpha    = (const float*)d_in[6];
    float* out = (float*)d_out;

    unsigned short* yT = (unsigned short*)d_ws;                       // 102,760,448 B
    short* wA  = (short*)((char*)d_ws + 102760448);                   //    294,912 B
    short* wAt = (short*)((char*)d_ws + 102760448 + 294912);          //     98,304 B

    repack_wsp<<<576, 256, 0, stream>>>(w_sp, wA);
    repack_wt2<<<192, 256, 0, stream>>>(w_t, wAt);
    spatial_mfma<<<dim3(4, 512), 512, 0, stream>>>(x, wA, b_sp, yT);
    temporal_mfma<<<dim3(7, 512), 256, 0, stream>>>(yT, wAt, b_t, alpha, x, vid_lens, out);
    write_lens<<<1, 64, 0, stream>>>(vid_lens, out);
}